// Round 2
// baseline (125.339 us; speedup 1.0000x reference)
//
#include <hip/hip_runtime.h>
#include <math.h>

#define TOPK_K 10
#define SEG 8
#define EPS_F 1e-9f
#define IOU_EPS_F 1e-7f

struct Iou6 { float ov; float ov6; };

// NOTE: contract(off) so all kernels compute bit-identical IoU/align values.
// The score==1 test in k_assign compares against k_topk's stored max; any
// cross-kernel FMA-contraction difference would break exact equality.
__device__ __forceinline__ Iou6 iou_pow6(float px1, float py1, float px2, float py2,
                                         float gx1, float gy1, float gx2, float gy2) {
#pragma clang fp contract(off)
  float ix1 = fmaxf(px1, gx1);
  float iy1 = fmaxf(py1, gy1);
  float ix2 = fminf(px2, gx2);
  float iy2 = fminf(py2, gy2);
  float dw = fmaxf(ix2 - ix1, 0.0f);
  float dh = fmaxf(iy2 - iy1, 0.0f);
  float inter = dw * dh;
  float a1 = (px2 - px1) * (py2 - py1);
  float a2 = (gx2 - gx1) * (gy2 - gy1);
  float den = a1 + a2 - inter + IOU_EPS_F;
  float iou = inter / den;
  float ov = fmaxf(iou, 0.0f);
  float ov2 = ov * ov;
  Iou6 r; r.ov = ov; r.ov6 = ov2 * ov2 * ov2;
  return r;
}

__device__ __forceinline__ float sigmoid_f(float x) {
#pragma clang fp contract(off)
  return 1.0f / (1.0f + expf(-x));
}

// ---------------------------------------------------------------------------
// Kernel 1a: per (b,m,seg) stable top-10 of align over the segment.
// 6144 blocks -> occupancy-bound latency hiding (was 768 blocks @ 21% occ).
// ---------------------------------------------------------------------------
__launch_bounds__(256)
__global__ void k_topk_seg(const float* __restrict__ pd_scores,
                           const float* __restrict__ pd_bboxes,
                           const int*   __restrict__ gt_labels,
                           const float* __restrict__ gt_bboxes,
                           const float* __restrict__ mask_gt,
                           int B, int N, int M, int C,
                           float* __restrict__ cand_v,   // [B*M*SEG*10]
                           int*   __restrict__ cand_i)   // [B*M*SEG*10]
{
  const int m = blockIdx.x, s = blockIdx.y, b = blockIdx.z;
  const int tid = threadIdx.x;
  const int bm = b * M + m;

  __shared__ float redv[4];
  __shared__ int   redi[4];

  if (mask_gt[bm] == 0.0f) return;     // k_merge handles masked rows

  const int seglen = (N + SEG - 1) / SEG;
  const int n0 = s * seglen;
  const int n1 = min(n0 + seglen, N);

  const float4 g = *(const float4*)(gt_bboxes + (size_t)bm * 4);
  int gl = gt_labels[bm];
  gl = min(max(gl, 0), C - 1);
  const float* __restrict__ srow = pd_scores + (size_t)b * N * C;

  // register ladder: lv sorted descending, ties keep earlier index
  float lv[TOPK_K]; int li[TOPK_K];
#pragma unroll
  for (int j = 0; j < TOPK_K; ++j) { lv[j] = -1.0f; li[j] = -1; }

  for (int n = n0 + tid; n < n1; n += 256) {
    const float4 p = *(const float4*)(pd_bboxes + ((size_t)b * N + n) * 4);
    Iou6 io = iou_pow6(p.x, p.y, p.z, p.w, g.x, g.y, g.z, g.w);
    // align = sigmoid(score)*ov^6 < ov^6 (sig<1), so ov6 <= lv[9] => skip is sound
    if (io.ov6 > lv[TOPK_K - 1]) {
      float a;
      if (io.ov6 == 0.0f) {
        a = 0.0f;                       // sig*0 == 0 exactly: skip the gather
      } else {
        float sc = srow[(size_t)n * C + gl];
        a = sigmoid_f(sc) * io.ov6;     // ALPHA=1, mg==1 here
      }
      if (a > lv[TOPK_K - 1]) {
        // unrolled stable insertion (all static indices -> stays in VGPRs)
#pragma unroll
        for (int j = TOPK_K - 1; j >= 0; --j) {
          bool shift = (j >= 1) && (a > lv[j - 1]);
          if (shift)            { lv[j] = lv[j - 1]; li[j] = li[j - 1]; }
          else if (a > lv[j])   { lv[j] = a;         li[j] = n; }
        }
      }
    }
  }

  // merge 256 ladders: 10 rounds of block-argmax over ladder heads.
  const int lane = tid & 63;
  const int wid  = tid >> 6;
  const size_t cbase = ((size_t)bm * SEG + s) * TOPK_K;
  for (int r = 0; r < TOPK_K; ++r) {
    float v = lv[0]; int ii = li[0];
#pragma unroll
    for (int off = 32; off > 0; off >>= 1) {
      float vv = __shfl_xor(v, off);
      int   jj = __shfl_xor(ii, off);
      if (vv > v || (vv == v && (unsigned)jj < (unsigned)ii)) { v = vv; ii = jj; }
    }
    if (lane == 0) { redv[wid] = v; redi[wid] = ii; }
    __syncthreads();
    float v4 = redv[0]; int i4 = redi[0];
#pragma unroll
    for (int w = 1; w < 4; ++w) {
      float vv = redv[w]; int jj = redi[w];
      if (vv > v4 || (vv == v4 && (unsigned)jj < (unsigned)i4)) { v4 = vv; i4 = jj; }
    }
    if (tid == 0) { cand_v[cbase + r] = v4; cand_i[cbase + r] = i4; }
    if (li[0] == i4 && lv[0] == v4) {   // unique owner pops (indices unique)
#pragma unroll
      for (int j = 0; j < TOPK_K - 1; ++j) { lv[j] = lv[j + 1]; li[j] = li[j + 1]; }
      lv[TOPK_K - 1] = -2.0f; li[TOPK_K - 1] = -1;
    }
    __syncthreads();
  }
}

// ---------------------------------------------------------------------------
// Kernel 1b: per (b,m) merge SEG*10 candidates -> final top-10 + row max.
// Segment winners are always real entries (val>=0), so sentinels never win.
// ---------------------------------------------------------------------------
__launch_bounds__(128)
__global__ void k_merge(const float* __restrict__ mask_gt,
                        const float* __restrict__ cand_v,
                        const int*   __restrict__ cand_i,
                        int B, int M,
                        int*   __restrict__ topk_idx,   // [B*M*10]
                        float* __restrict__ maxv_out)   // [B*M]
{
  const int m = blockIdx.x, b = blockIdx.y;
  const int bm = b * M + m;
  const int tid = threadIdx.x;

  __shared__ float redv[2];
  __shared__ int   redi[2];

  if (mask_gt[bm] == 0.0f) {
    if (tid < TOPK_K) topk_idx[bm * TOPK_K + tid] = -1;
    if (tid == 0) maxv_out[bm] = 0.0f;
    return;
  }

  float v = -3.0f; int ii = -1;
  if (tid < SEG * TOPK_K) {
    v  = cand_v[(size_t)bm * SEG * TOPK_K + tid];
    ii = cand_i[(size_t)bm * SEG * TOPK_K + tid];
  }

  const int lane = tid & 63;
  const int wid  = tid >> 6;
  bool keep = false;
  for (int r = 0; r < TOPK_K; ++r) {
    float v2 = v; int i2 = ii;
#pragma unroll
    for (int off = 32; off > 0; off >>= 1) {
      float vv = __shfl_xor(v2, off);
      int   jj = __shfl_xor(i2, off);
      if (vv > v2 || (vv == v2 && (unsigned)jj < (unsigned)i2)) { v2 = vv; i2 = jj; }
    }
    if (lane == 0) { redv[wid] = v2; redi[wid] = i2; }
    __syncthreads();
    float v4 = redv[0]; int i4 = redi[0];
    {
      float vv = redv[1]; int jj = redi[1];
      if (vv > v4 || (vv == v4 && (unsigned)jj < (unsigned)i4)) { v4 = vv; i4 = jj; }
    }
    if (r == 0) {
      float maxv = fmaxf(v4, 0.0f);
      keep = maxv > EPS_F;              // keep = topk_vals.max > EPS
      if (tid == 0) maxv_out[bm] = maxv;
    }
    if (tid == 0) topk_idx[bm * TOPK_K + r] = keep ? i4 : -1;
    if (v == v4 && ii == i4) v = -3.0f; // pop (idx unique across segments)
    __syncthreads();
  }
}

// ---------------------------------------------------------------------------
// Kernel 2: per-anchor assignment + all outputs. (unchanged from R1)
// ---------------------------------------------------------------------------
__launch_bounds__(256)
__global__ void k_assign(const float* __restrict__ pd_scores,
                         const float* __restrict__ pd_bboxes,
                         const float* __restrict__ anchors,
                         const int*   __restrict__ gt_labels,
                         const float* __restrict__ gt_bboxes,
                         const float* __restrict__ mask_gt,
                         const int*   __restrict__ topk_idx,
                         const float* __restrict__ maxv_in,
                         int B, int N, int M, int C,
                         float* __restrict__ out)
{
  const int b = blockIdx.y;
  const int chunk0 = blockIdx.x * 256;
  const int tid = threadIdx.x;

  __shared__ float4   sgt[128];
  __shared__ int      sgl[128];
  __shared__ float    smg[128];
  __shared__ float    smpg[128];
  __shared__ float    spre[128];
  __shared__ unsigned sbm[128 * 8];   // membership bitmap: 256 anchors per m
  __shared__ int      slab[256];
  __shared__ float    ssv[256];

  if (tid < M) {
    sgt[tid] = *(const float4*)(gt_bboxes + (size_t)(b * M + tid) * 4);
    sgl[tid] = min(max(gt_labels[b * M + tid], 0), C - 1);
    smg[tid] = mask_gt[b * M + tid];
    float mv  = maxv_in[b * M + tid];
    float mpg = fmaxf(mv, EPS_F);       // clip(align.max, EPS)
    smpg[tid] = mpg;
    spre[tid] = mpg * 0.999999f;        // prefilter: q>=1 needs ov6 > mpg*(1-2^-23)
  }
  for (int i = tid; i < M * 8; i += 256) sbm[i] = 0u;
  __syncthreads();
  for (int t = tid; t < M * TOPK_K; t += 256) {
    int e = topk_idx[(size_t)(b * M) * TOPK_K + t];
    int rel = e - chunk0;
    if (rel >= 0 && rel < 256)
      atomicOr(&sbm[(t / TOPK_K) * 8 + (rel >> 5)], 1u << (rel & 31));
  }
  __syncthreads();

  float* __restrict__ out_bbox   = out;
  float* __restrict__ out_scores = out + (size_t)B * N * 4;
  float* __restrict__ out_fg     = out_scores + (size_t)B * N * C;
  float* __restrict__ out_tgt    = out_fg + (size_t)B * N;

  const int n = chunk0 + tid;
  int lab = 0; float sval = 0.0f;
  if (n < N) {
    const float4 p = *(const float4*)(pd_bboxes + ((size_t)b * N + n) * 4);
    const float ax = anchors[(size_t)n * 2];
    const float ay = anchors[(size_t)n * 2 + 1];
    const float* __restrict__ srow = pd_scores + ((size_t)b * N + n) * C;

    float ovmax = -1.0f; int ovarg = 0;
    int cnt = 0, firstpos = -1; bool one = false;

    for (int m = 0; m < M; ++m) {
      const float4 g = sgt[m];
      Iou6 io = iou_pow6(p.x, p.y, p.z, p.w, g.x, g.y, g.z, g.w);
      if (io.ov > ovmax) { ovmax = io.ov; ovarg = m; }   // first-occurrence argmax
      const float mgv = smg[m];
      const float d = fminf(fminf(ax - g.x, ay - g.y), fminf(g.z - ax, g.w - ay));
      const unsigned w = sbm[m * 8 + (tid >> 5)];
      const bool member = (w >> (tid & 31)) & 1u;
      if ((d > EPS_F) && member && (mgv > 0.0f)) {
        cnt++;
        if (firstpos < 0) firstpos = m;
      }
      // norm_align only matters via int32-truncation: test q >= 1.0 exactly,
      // prefiltered (align = sig*ov6 <= ov6) so the gather is rare.
      if ((mgv > 0.0f) && (io.ov6 >= spre[m])) {
        float a = sigmoid_f(srow[sgl[m]]) * io.ov6;      // identical expr to k_topk
        if (a / smpg[m] >= 1.0f) one = true;
      }
    }

    float fg; int tgt;
    if (cnt > 1)      { fg = 1.0f; tgt = ovarg; }        // where(multi, is_max, ...)
    else if (cnt == 1){ fg = 1.0f; tgt = firstpos; }
    else              { fg = 0.0f; tgt = 0; }            // argmax of all-zero row = 0

    lab  = sgl[tgt];
    sval = (fg > 0.0f && one) ? 1.0f : 0.0f;

    *(float4*)(out_bbox + ((size_t)b * N + n) * 4) = sgt[tgt];
    out_fg[(size_t)b * N + n]  = fg;
    out_tgt[(size_t)b * N + n] = (float)tgt;
  }
  slab[tid] = lab; ssv[tid] = sval;
  __syncthreads();

  // cooperative coalesced write of the (rows x C) score tile
  const int rows = min(256, N - chunk0);
  const int c4n = C >> 2;
  float4* __restrict__ os4 = (float4*)(out_scores + ((size_t)b * N + chunk0) * C);
  const int tot = rows * c4n;
  for (int i = tid; i < tot; i += 256) {
    int row = i / c4n;
    int c0 = (i - row * c4n) * 4;
    int lr = slab[row]; float v = ssv[row];
    float4 o;
    o.x = (c0     == lr) ? v : 0.0f;
    o.y = (c0 + 1 == lr) ? v : 0.0f;
    o.z = (c0 + 2 == lr) ? v : 0.0f;
    o.w = (c0 + 3 == lr) ? v : 0.0f;
    os4[i] = o;
  }
}

extern "C" void kernel_launch(void* const* d_in, const int* in_sizes, int n_in,
                              void* d_out, int out_size, void* d_ws, size_t ws_size,
                              hipStream_t stream) {
  const float* pd_scores = (const float*)d_in[0];
  const float* pd_bboxes = (const float*)d_in[1];
  const float* anchors   = (const float*)d_in[2];
  const int*   gt_labels = (const int*)d_in[3];
  const float* gt_bboxes = (const float*)d_in[4];
  const float* mask_gt   = (const float*)d_in[5];

  const int N = in_sizes[2] / 2;               // anchor_points (N,2)
  const int B = in_sizes[1] / (N * 4);         // pd_bboxes (B,N,4)
  const int M = in_sizes[3] / B;               // gt_labels (B,M,1)
  const int C = in_sizes[0] / (B * N);         // pd_scores (B,N,C)

  char* ws = (char*)d_ws;
  int*   topk   = (int*)ws;                    ws += (size_t)B * M * TOPK_K * sizeof(int);
  float* maxv   = (float*)ws;                  ws += (size_t)B * M * sizeof(float);
  float* cand_v = (float*)ws;                  ws += (size_t)B * M * SEG * TOPK_K * sizeof(float);
  int*   cand_i = (int*)ws;

  dim3 g1(M, SEG, B);
  k_topk_seg<<<g1, 256, 0, stream>>>(pd_scores, pd_bboxes, gt_labels, gt_bboxes,
                                     mask_gt, B, N, M, C, cand_v, cand_i);

  dim3 gm(M, B);
  k_merge<<<gm, 128, 0, stream>>>(mask_gt, cand_v, cand_i, B, M, topk, maxv);

  dim3 g2((N + 255) / 256, B);
  k_assign<<<g2, 256, 0, stream>>>(pd_scores, pd_bboxes, anchors, gt_labels,
                                   gt_bboxes, mask_gt, topk, maxv,
                                   B, N, M, C, (float*)d_out);
}

// Round 3
// 93.583 us; speedup vs baseline: 1.3393x; 1.3393x over previous
//
#include <hip/hip_runtime.h>
#include <math.h>

#define TOPK_K 10
#define EPS_F 1e-9f
#define IOU_EPS_F 1e-7f
#define CH 128          // anchors per k_assign block

struct Iou6 { float ov; float ov6; };

// NOTE: contract(off) so all kernels compute bit-identical IoU/align values.
// Membership (a==T) and the q>=1 test compare values computed in different
// kernels; any cross-kernel FMA-contraction difference would break equality.
__device__ __forceinline__ Iou6 iou_pow6(float px1, float py1, float px2, float py2,
                                         float gx1, float gy1, float gx2, float gy2) {
#pragma clang fp contract(off)
  float ix1 = fmaxf(px1, gx1);
  float iy1 = fmaxf(py1, gy1);
  float ix2 = fminf(px2, gx2);
  float iy2 = fminf(py2, gy2);
  float dw = fmaxf(ix2 - ix1, 0.0f);
  float dh = fmaxf(iy2 - iy1, 0.0f);
  float inter = dw * dh;
  float a1 = (px2 - px1) * (py2 - py1);
  float a2 = (gx2 - gx1) * (gy2 - gy1);
  float den = a1 + a2 - inter + IOU_EPS_F;
  float iou = inter / den;
  float ov = fmaxf(iou, 0.0f);
  float ov2 = ov * ov;
  Iou6 r; r.ov = ov; r.ov6 = ov2 * ov2 * ov2;
  return r;
}

__device__ __forceinline__ float sigmoid_f(float x) {
#pragma clang fp contract(off)
  return 1.0f / (1.0f + expf(-x));
}

// stable ladder insert: sorted desc, ties keep earlier index (static indices)
#define PROC(p, nn)                                                            \
  {                                                                            \
    Iou6 io = iou_pow6((p).x, (p).y, (p).z, (p).w, g.x, g.y, g.z, g.w);        \
    if (io.ov6 > lv[TOPK_K - 1]) {                                             \
      float a;                                                                 \
      if (io.ov6 == 0.0f) a = 0.0f;                                            \
      else { float sc = srow[(size_t)(nn) * C + gl]; a = sigmoid_f(sc) * io.ov6; } \
      if (a > lv[TOPK_K - 1]) {                                                \
        _Pragma("unroll")                                                      \
        for (int j = TOPK_K - 1; j >= 0; --j) {                                \
          bool shift = (j >= 1) && (a > lv[j - 1]);                            \
          if (shift)          { lv[j] = lv[j - 1]; li[j] = li[j - 1]; }        \
          else if (a > lv[j]) { lv[j] = a;         li[j] = (nn); }             \
        }                                                                      \
      }                                                                        \
    }                                                                          \
  }

// key: (ordered float bits << 32) | ~idx  -- larger = (bigger v, smaller idx).
// v >= 0 always for real entries; sentinel (idx<0) -> key 0.
__device__ __forceinline__ unsigned long long mk_key(float v, int idx) {
  if (idx < 0) return 0ull;
  unsigned uv = __float_as_uint(v) | 0x80000000u;
  return ((unsigned long long)uv << 32) | (unsigned)(~idx);
}

// ---------------------------------------------------------------------------
// Kernel 1: per (b,m) row -> maxv (top-1 align), (T,I) = 10th (value,index).
// 768 blocks x 512 threads; x4-unrolled scan; u64-key merge (10 rounds).
// ---------------------------------------------------------------------------
__launch_bounds__(512)
__global__ void k_topk(const float* __restrict__ pd_scores,
                       const float* __restrict__ pd_bboxes,
                       const int*   __restrict__ gt_labels,
                       const float* __restrict__ gt_bboxes,
                       const float* __restrict__ mask_gt,
                       int B, int N, int M, int C,
                       float* __restrict__ maxv_out,   // [B*M]
                       float* __restrict__ t10v_out,   // [B*M]
                       int*   __restrict__ t10i_out)   // [B*M]
{
  const int m = blockIdx.x, b = blockIdx.y;
  const int tid = threadIdx.x;
  const int bm = b * M + m;

  __shared__ unsigned long long sred[8];

  if (mask_gt[bm] == 0.0f) {
    if (tid == 0) { maxv_out[bm] = 0.0f; t10v_out[bm] = 0.0f; t10i_out[bm] = -1; }
    return;
  }

  const float4 g = *(const float4*)(gt_bboxes + (size_t)bm * 4);
  int gl = gt_labels[bm];
  gl = min(max(gl, 0), C - 1);
  const float* __restrict__ srow = pd_scores + (size_t)b * N * C;
  const float4* __restrict__ pb = (const float4*)(pd_bboxes + (size_t)b * N * 4);

  float lv[TOPK_K]; int li[TOPK_K];
#pragma unroll
  for (int j = 0; j < TOPK_K; ++j) { lv[j] = -1.0f; li[j] = -1; }

  // x4-unrolled scan: 4 independent float4 loads in flight per iteration
  int n = tid;
  for (; n + 3 * 512 < N; n += 4 * 512) {
    float4 p0 = pb[n];
    float4 p1 = pb[n + 512];
    float4 p2 = pb[n + 1024];
    float4 p3 = pb[n + 1536];
    PROC(p0, n);
    PROC(p1, n + 512);
    PROC(p2, n + 1024);
    PROC(p3, n + 1536);
  }
  for (; n < N; n += 512) {
    float4 p = pb[n];
    PROC(p, n);
  }

  // 10 rounds of block-wide u64-key max (wave shfl + 8-entry LDS cross-wave)
  const int lane = tid & 63;
  const int wid  = tid >> 6;
  for (int r = 0; r < TOPK_K; ++r) {
    const unsigned long long kmine = mk_key(lv[0], li[0]);
    unsigned long long k = kmine;
#pragma unroll
    for (int off = 32; off > 0; off >>= 1) {
      unsigned long long o = __shfl_xor(k, off);
      if (o > k) k = o;
    }
    if (lane == 0) sred[wid] = k;
    __syncthreads();
    unsigned long long kw = sred[0];
#pragma unroll
    for (int w = 1; w < 8; ++w) { unsigned long long o = sred[w]; if (o > kw) kw = o; }

    if (tid == 0) {
      float v = __uint_as_float(((unsigned)(kw >> 32)) & 0x7fffffffu);
      if (r == 0) maxv_out[bm] = v;
      if (r == TOPK_K - 1) {
        t10v_out[bm] = v;
        t10i_out[bm] = (int)~(unsigned)(kw & 0xffffffffu);
      }
    }
    if (kmine == kw) {   // unique owner pops (keys unique: idx distinct)
#pragma unroll
      for (int j = 0; j < TOPK_K - 1; ++j) { lv[j] = lv[j + 1]; li[j] = li[j + 1]; }
      lv[TOPK_K - 1] = -2.0f; li[TOPK_K - 1] = -1;
    }
    __syncthreads();
  }
}

// ---------------------------------------------------------------------------
// Kernel 2: per-anchor assignment + all outputs.
// 256 threads = 128 anchors x 2 m-half-ranges; partials merged via LDS.
// Membership by rank test vs (T,I): a>T || (a==T && n<=I); zeros case n<=I.
// ---------------------------------------------------------------------------
__launch_bounds__(256)
__global__ void k_assign(const float* __restrict__ pd_scores,
                         const float* __restrict__ pd_bboxes,
                         const float* __restrict__ anchors,
                         const int*   __restrict__ gt_labels,
                         const float* __restrict__ gt_bboxes,
                         const float* __restrict__ mask_gt,
                         const float* __restrict__ maxv_in,
                         const float* __restrict__ t10v_in,
                         const int*   __restrict__ t10i_in,
                         int B, int N, int M, int C,
                         float* __restrict__ out)
{
  const int b = blockIdx.y;
  const int chunk0 = blockIdx.x * CH;
  const int tid = threadIdx.x;
  const int al   = tid & (CH - 1);   // anchor-local
  const int half = tid >> 7;         // which m-half this thread covers
  const int n = chunk0 + al;

  __shared__ float4 sgt[128];
  __shared__ int    sgl[128];
  __shared__ float  smg[128];
  __shared__ float  smpg[128];
  __shared__ float  spre[128];
  __shared__ float  smT[128];
  __shared__ int    smI[128];
  __shared__ int    skeep[128];
  __shared__ float  s_pov[CH];
  __shared__ int    s_parg[CH], s_pcnt[CH], s_pfirst[CH], s_pone[CH];
  __shared__ int    slab[CH];
  __shared__ float  ssv[CH];

  if (tid < M) {
    sgt[tid] = *(const float4*)(gt_bboxes + (size_t)(b * M + tid) * 4);
    sgl[tid] = min(max(gt_labels[b * M + tid], 0), C - 1);
    smg[tid] = mask_gt[b * M + tid];
    float mv  = maxv_in[b * M + tid];
    float mpg = fmaxf(mv, EPS_F);       // clip(align.max, EPS)
    smpg[tid] = mpg;
    spre[tid] = mpg * 0.999999f;        // q>=1 prefilter (below any rounding)
    smT[tid]  = t10v_in[b * M + tid];
    smI[tid]  = t10i_in[b * M + tid];
    skeep[tid] = (mv > EPS_F) ? 1 : 0;  // keep = topk max > EPS
  }
  __syncthreads();

  float* __restrict__ out_bbox   = out;
  float* __restrict__ out_scores = out + (size_t)B * N * 4;
  float* __restrict__ out_fg     = out_scores + (size_t)B * N * C;
  float* __restrict__ out_tgt    = out_fg + (size_t)B * N;

  const bool valid = (n < N);
  float pov = -1.0f; int parg = 0;
  int pcnt = 0, pfirst = -1, pone = 0;

  if (valid) {
    const float4 p = *(const float4*)(pd_bboxes + ((size_t)b * N + n) * 4);
    const float ax = anchors[(size_t)n * 2];
    const float ay = anchors[(size_t)n * 2 + 1];
    const float* __restrict__ srow = pd_scores + ((size_t)b * N + n) * C;

    const int mhalf = (M + 1) >> 1;
    const int mlo = half ? mhalf : 0;
    const int mhi = half ? M : mhalf;

    for (int m = mlo; m < mhi; ++m) {
      const float4 gbb = sgt[m];
      Iou6 io = iou_pow6(p.x, p.y, p.z, p.w, gbb.x, gbb.y, gbb.z, gbb.w);
      if (io.ov > pov) { pov = io.ov; parg = m; }   // first-occurrence argmax
      const float mgv = smg[m];
      if (mgv > 0.0f) {
        const float T = smT[m];
        const int keep = skeep[m];
        bool mem = false;
        const bool cand = keep && (io.ov6 > T);     // align < ov6 (sig<1)
        if (cand || (io.ov6 >= spre[m])) {
          const float a = sigmoid_f(srow[sgl[m]]) * io.ov6;  // == k_topk's a
          if (cand) mem = (a > T) || (a == T && n <= smI[m]);
          if (a / smpg[m] >= 1.0f) pone = 1;        // int32(norm_align)==1
        } else if (keep && (T == 0.0f) && (io.ov6 == 0.0f)) {
          mem = (n <= smI[m]);                      // zero-valued tail of top-10
        }
        if (mem) {
          const float d = fminf(fminf(ax - gbb.x, ay - gbb.y),
                                fminf(gbb.z - ax, gbb.w - ay));
          if (d > EPS_F) { pcnt++; if (pfirst < 0) pfirst = m; }
        }
      }
    }
  }

  if (half == 1 && valid) {
    s_pov[al] = pov; s_parg[al] = parg; s_pcnt[al] = pcnt;
    s_pfirst[al] = pfirst; s_pone[al] = pone;
  }
  __syncthreads();

  if (half == 0 && valid) {
    // merge halves: half0 wins ov ties (lower m = first occurrence)
    float ov1 = s_pov[al];
    if (ov1 > pov) { pov = ov1; parg = s_parg[al]; }
    pcnt += s_pcnt[al];
    if (pfirst < 0) pfirst = s_pfirst[al];
    pone |= s_pone[al];

    float fg; int tgt;
    if (pcnt > 1)       { fg = 1.0f; tgt = parg; }     // where(multi, is_max, .)
    else if (pcnt == 1) { fg = 1.0f; tgt = pfirst; }
    else                { fg = 0.0f; tgt = 0; }        // argmax of zero row = 0

    slab[al] = sgl[tgt];
    ssv[al]  = (fg > 0.0f && pone) ? 1.0f : 0.0f;

    *(float4*)(out_bbox + ((size_t)b * N + n) * 4) = sgt[tgt];
    out_fg[(size_t)b * N + n]  = fg;
    out_tgt[(size_t)b * N + n] = (float)tgt;
  }
  __syncthreads();

  // cooperative coalesced write of the (rows x C) score tile
  const int rows = min(CH, N - chunk0);
  const int c4n = C >> 2;
  float4* __restrict__ os4 = (float4*)(out_scores + ((size_t)b * N + chunk0) * C);
  const int tot = rows * c4n;
  for (int i = tid; i < tot; i += 256) {
    int row = i / c4n;
    int c0 = (i - row * c4n) * 4;
    int lr = slab[row]; float v = ssv[row];
    float4 o;
    o.x = (c0     == lr) ? v : 0.0f;
    o.y = (c0 + 1 == lr) ? v : 0.0f;
    o.z = (c0 + 2 == lr) ? v : 0.0f;
    o.w = (c0 + 3 == lr) ? v : 0.0f;
    os4[i] = o;
  }
}

extern "C" void kernel_launch(void* const* d_in, const int* in_sizes, int n_in,
                              void* d_out, int out_size, void* d_ws, size_t ws_size,
                              hipStream_t stream) {
  const float* pd_scores = (const float*)d_in[0];
  const float* pd_bboxes = (const float*)d_in[1];
  const float* anchors   = (const float*)d_in[2];
  const int*   gt_labels = (const int*)d_in[3];
  const float* gt_bboxes = (const float*)d_in[4];
  const float* mask_gt   = (const float*)d_in[5];

  const int N = in_sizes[2] / 2;               // anchor_points (N,2)
  const int B = in_sizes[1] / (N * 4);         // pd_bboxes (B,N,4)
  const int M = in_sizes[3] / B;               // gt_labels (B,M,1)
  const int C = in_sizes[0] / (B * N);         // pd_scores (B,N,C)

  char* ws = (char*)d_ws;
  float* maxv = (float*)ws;                    ws += (size_t)B * M * sizeof(float);
  float* t10v = (float*)ws;                    ws += (size_t)B * M * sizeof(float);
  int*   t10i = (int*)ws;

  dim3 g1(M, B);
  k_topk<<<g1, 512, 0, stream>>>(pd_scores, pd_bboxes, gt_labels, gt_bboxes,
                                 mask_gt, B, N, M, C, maxv, t10v, t10i);

  dim3 g2((N + CH - 1) / CH, B);
  k_assign<<<g2, 256, 0, stream>>>(pd_scores, pd_bboxes, anchors, gt_labels,
                                   gt_bboxes, mask_gt, maxv, t10v, t10i,
                                   B, N, M, C, (float*)d_out);
}